// Round 8
// baseline (3918.358 us; speedup 1.0000x reference)
//
#include <hip/hip_runtime.h>
#include <hip/hip_fp16.h>

typedef _Float16 f16;
typedef _Float16 f16x8 __attribute__((ext_vector_type(8)));
typedef _Float16 f16x4 __attribute__((ext_vector_type(4)));
typedef float    f32x4 __attribute__((ext_vector_type(4)));
typedef unsigned long long u64;
typedef u64 u64x2 __attribute__((ext_vector_type(2)));

#define TT 512
#define BB 256
#define HH 256

// ---- workspace byte offsets ----
#define O_WFRAG_ENC 0u
#define O_WFRAG_M   393216u
#define O_WFRAG_P   786432u
#define O_WFRAG_GI  1179648u
#define O_HE_ST     1966080u
#define O_HM_ST     2097152u
#define O_HP_ST     2228224u
#define O_HPSUM     2359296u
#define O_XCHG      2621440u   // 3 recs *16 bt *2 roles *2 parity * 4096 B = 786432
#define O_FLAGS     3407872u   // 96 ints, padded to 1024
#define O_DYN       3408896u
#define DYN_PER_STEP 917504u   // he_buf 131072 + gi_buf 786432 per step

__device__ __forceinline__ float sigf(float x){ return 1.0f/(1.0f+__expf(-x)); }
__device__ __forceinline__ float tanh_(float x){
  float xc = fminf(fmaxf(x,-15.f),15.f);
  float e  = __expf(2.f*xc);
  return (e-1.f)/(e+1.f);
}
// XOR-swizzled element index into a [16][256] f16 tile (16B granules ^ row&7)
__device__ __forceinline__ int hswz(int row, int j){
  return row*256 + ((((j>>3) ^ (row&7)))<<3) + (j&7);
}

// =====================================================================
// PREP: weights -> f16 fragment buffers, init states, zero pair flags
// =====================================================================
__global__ void prep_kernel(
    const float* __restrict__ enc_whh, const float* __restrict__ mdec_whh,
    const float* __restrict__ pdec_whh, const float* __restrict__ mdec_wih,
    const float* __restrict__ pdec_wih,
    const float* __restrict__ h0e, const float* __restrict__ h0m, const float* __restrict__ h0p,
    f16* __restrict__ wfrag_enc, f16* __restrict__ wfrag_m, f16* __restrict__ wfrag_p,
    f16* __restrict__ wfrag_gi,
    f16* __restrict__ he_st, f16* __restrict__ hm_st, f16* __restrict__ hp_st,
    float* __restrict__ hpsum, int* __restrict__ flags)
{
  int idx = blockIdx.x*256 + threadIdx.x;
  const int NW = 16*3*8*64*8; // 196608
  if (idx < 3*NW){
    int b = idx / NW, e = idx % NW;
    int jj = e & 7, l = (e>>3)&63, ks = (e>>9)&7, t2 = e>>12;
    int g = t2 % 3, w = t2 / 3;
    int row = g*256 + w*16 + (l&15);
    int col = ks*32 + (l>>4)*8 + jj;
    const float* W = (b==0)?enc_whh:((b==1)?mdec_whh:pdec_whh);
    f16* D = (b==0)?wfrag_enc:((b==1)?wfrag_m:wfrag_p);
    D[e] = (f16)W[row*256+col];
    return;
  }
  idx -= 3*NW;
  const int NG = 96*8*64*8; // 393216
  if (idx < NG){
    int e = idx;
    int jj = e&7, l=(e>>3)&63, ks=(e>>9)&7, mt = e>>12;
    int row = mt*16 + (l&15);
    int col = ks*32 + (l>>4)*8 + jj;
    float v = (row < 768) ? mdec_wih[row*256+col] : pdec_wih[(row-768)*256+col];
    wfrag_gi[e] = (f16)v;
    return;
  }
  idx -= NG;
  if (idx < 65536){
    he_st[idx] = (f16)h0e[idx];
    hm_st[idx] = (f16)h0m[idx];
    hp_st[idx] = (f16)h0p[idx];
    hpsum[idx] = 0.f;
    if (idx < 96) flags[idx] = 0;
  }
}

// =====================================================================
// Recurrence core. MODE 0=encoder, 1=mask-dec, 2=pred-dec.
// PAIRED WGs: 256 threads (4 waves), role in {0,1} owns j-half
// [role*128, role*128+128). wf[2][3][8]=192 VGPRs under the PROVEN
// 256-reg budget of 4-wave WGs. Full h lives in LDS (double-buffered);
// halves are exchanged each step through L2 with agent-scope atomics
// and a monotone per-pair flag counter (zeroed by prep each launch).
// =====================================================================
template<int MODE>
__device__ __forceinline__ void gru_run(
  int role, int bt, int slice, int SL,
  const f16* __restrict__ wfrag,
  const float* __restrict__ bih, const float* __restrict__ bhh,
  const float* __restrict__ enc_wih,
  const float* __restrict__ seq, const float* __restrict__ dpad,
  const f16* __restrict__ gi_src,        // pre-offset for (bt, rec); bih folded in
  f16* __restrict__ h_state,
  f16* __restrict__ he_buf,
  const float* __restrict__ mlin_w, const float* __restrict__ mlin_b,
  float* __restrict__ out_mask,
  float* __restrict__ hpsum,
  u64* __restrict__ xchg, int* __restrict__ flags,
  unsigned char* smem)
{
  const int tid = threadIdx.x;       // 256
  const int lane = tid & 63;
  const int wid  = tid >> 6;         // 0..3
  const int l15  = lane & 15;
  const int lhi  = lane >> 4;
  const int bi0  = lhi*4;
  const int b0   = bt*16;
  constexpr int FREC = (MODE==1) ? 0 : ((MODE==2) ? 1 : 2);

  f16* hbuf   = (f16*)smem;                 // [2][16*256] swizzled (16 KB)
  float* xb   = (float*)(smem + 16384);     // [2][16] (enc)
  float* mlwf = xb + 32;                    // [256] f32 (mdec role0)

  // ---- resident B-fragments: j-block = role*8 + wid*2 + q
  f16x8 wf[2][3][8];
  #pragma unroll
  for (int q=0;q<2;++q){
    const int w = role*8 + wid*2 + q;
    #pragma unroll
    for (int g=0;g<3;++g)
      #pragma unroll
      for (int ks=0;ks<8;++ks)
        wf[q][g][ks] = *(const f16x8*)(wfrag + ((size_t)(((w*3+g)*8)+ks)*64 + lane)*8);
  }
  #pragma unroll
  for (int q=0;q<2;++q)
    #pragma unroll
    for (int g=0;g<3;++g)
      #pragma unroll
      for (int ks=0;ks<8;++ks)
        asm volatile("" : "+v"(wf[q][g][ks]));

  // ---- biases (dec: bih already folded into gi by gi_kernel)
  float cr[2], cz[2], cnh[2], cni[2];
  float wr_[2], wz_[2], wn_[2];
  #pragma unroll
  for (int q=0;q<2;++q){
    const int j = (role*8 + wid*2 + q)*16 + l15;
    if (MODE==0){
      cr[q]  = bih[j]     + bhh[j];
      cz[q]  = bih[256+j] + bhh[256+j];
      cnh[q] = bhh[512+j];
      cni[q] = bih[512+j];
      wr_[q]=enc_wih[j]; wz_[q]=enc_wih[256+j]; wn_[q]=enc_wih[512+j];
    } else {
      cr[q]  = bhh[j];
      cz[q]  = bhh[256+j];
      cnh[q] = bhh[512+j];
    }
  }
  float mlb = 0.f;
  if (MODE==1 && role==0){
    mlwf[tid] = mlin_w[tid];
    mlb = mlin_b[0];
  }

  // ---- initial FULL h -> hbuf[0]
  for (int jb=wid; jb<16; jb+=4){
    const int j = jb*16 + l15;
    #pragma unroll
    for (int r=0;r<4;++r)
      hbuf[hswz(bi0+r, j)] = h_state[(size_t)(b0+bi0+r)*256 + j];
  }
  if (MODE==0){
    if (tid<16){
      const int t = slice*SL;
      xb[tid] = (t==0) ? dpad[b0+tid] : seq[(size_t)(t-1)*BB + b0 + tid];
    }
  }
  __syncthreads();

  float psum[2][4];
  if (MODE==2){
    #pragma unroll
    for (int q=0;q<2;++q)
      #pragma unroll
      for (int r=0;r<4;++r) psum[q][r]=0.f;
  }

  const int fmy = (FREC*16 + bt)*2 + role;
  const int fpt = (FREC*16 + bt)*2 + (1-role);
  int* myf = flags + fmy;
  int* ptf = flags + fpt;

  for (int ts=0; ts<SL; ++ts){
    const int cur = ts & 1;
    f16* hc = hbuf + cur*4096;
    f16* hn = hbuf + (cur^1)*4096;
    const int gstep = slice*SL + ts;

    // early gi loads (dec) / x prefetch (enc)
    f16x4 gv[2][3];
    if (MODE!=0){
      const f16* gts = gi_src + (size_t)ts*393216u;
      #pragma unroll
      for (int q=0;q<2;++q)
        #pragma unroll
        for (int g=0;g<3;++g)
          gv[q][g] = *(const f16x4*)(gts + ((size_t)(g*256 + (role*8+wid*2+q)*16 + l15))*16 + bi0);
    } else {
      if (tid<16 && ts+1<SL)
        xb[(cur^1)*16 + tid] = seq[(size_t)(slice*SL + ts)*BB + b0 + tid];
    }

    // mask for previous step (mdec role0): full h is in hc
    if (MODE==1 && role==0 && ts>0){
      const int mb = tid>>4, jj = tid&15;
      float s = 0.f;
      #pragma unroll
      for (int k=0;k<16;++k){ const int j = jj + k*16; s += (float)hc[hswz(mb, j)]*mlwf[j]; }
      s += __shfl_xor(s,1,64); s += __shfl_xor(s,2,64);
      s += __shfl_xor(s,4,64); s += __shfl_xor(s,8,64);
      if (jj==0) out_mask[(size_t)(slice*SL + ts-1)*BB + b0 + mb] = s + mlb;
    }

    // ---- MFMA + gates (own j-half)
    #pragma unroll
    for (int q=0;q<2;++q){
      const int j = (role*8 + wid*2 + q)*16 + l15;
      f32x4 a0 = {cr[q],cr[q],cr[q],cr[q]};
      f32x4 a1 = {cz[q],cz[q],cz[q],cz[q]};
      f32x4 a2 = {cnh[q],cnh[q],cnh[q],cnh[q]};
      #pragma unroll
      for (int ks=0;ks<8;++ks){
        const f16x8 a = *(const f16x8*)(hc + l15*256 + ((((ks*4+lhi) ^ (l15&7)))<<3));
        a0 = __builtin_amdgcn_mfma_f32_16x16x32_f16(a, wf[q][0][ks], a0, 0,0,0);
        a1 = __builtin_amdgcn_mfma_f32_16x16x32_f16(a, wf[q][1][ks], a1, 0,0,0);
        a2 = __builtin_amdgcn_mfma_f32_16x16x32_f16(a, wf[q][2][ks], a2, 0,0,0);
      }
      float gir[4], giz[4], gin[4];
      if (MODE==0){
        #pragma unroll
        for (int r=0;r<4;++r){
          const float x = xb[cur*16 + bi0 + r];
          gir[r]=x*wr_[q]; giz[r]=x*wz_[q]; gin[r]=x*wn_[q] + cni[q];
        }
      } else {
        #pragma unroll
        for (int r=0;r<4;++r){
          gir[r]=(float)gv[q][0][r]; giz[r]=(float)gv[q][1][r]; gin[r]=(float)gv[q][2][r];
        }
      }
      #pragma unroll
      for (int r=0;r<4;++r){
        const int sz = hswz(bi0+r, j);
        const float hprev = (float)hc[sz];
        const float rr = sigf(gir[r] + a0[r]);
        const float zz = sigf(giz[r] + a1[r]);
        const float nn = tanh_(gin[r] + rr*a2[r]);
        const float h  = (1.f-zz)*nn + zz*hprev;
        hn[sz] = (f16)h;
        if (MODE==0) he_buf[((size_t)ts*BB + (b0+bi0+r))*HH + j] = (f16)h;
        if (MODE==2) psum[q][r] += h;
      }
    }
    __syncthreads();                                        // A: hn own half done

    // ---- pack own half -> xchg (agent-scope atomics)
    {
      const int trow = tid>>4, tgl = tid&15;
      const int glo = tgl + role*16;
      const f16* sp = hn + trow*256 + ((glo ^ (trow&7))<<3);
      const u64x2 v = *(const u64x2*)sp;
      u64* dm = xchg + ((size_t)(fmy*2 + cur))*512 + tid*2;
      __hip_atomic_store(dm+0, v[0], __ATOMIC_RELAXED, __HIP_MEMORY_SCOPE_AGENT);
      __hip_atomic_store(dm+1, v[1], __ATOMIC_RELAXED, __HIP_MEMORY_SCOPE_AGENT);
    }
    __syncthreads();                                        // B: stores drained
    if (tid==0){
      __hip_atomic_store(myf, gstep+1, __ATOMIC_RELEASE, __HIP_MEMORY_SCOPE_AGENT);
      while (__hip_atomic_load(ptf, __ATOMIC_ACQUIRE, __HIP_MEMORY_SCOPE_AGENT) < gstep+1)
        __builtin_amdgcn_s_sleep(1);
    }
    __syncthreads();                                        // C: partner ready
    {
      const int trow = tid>>4, tgl = tid&15;
      const u64* dp = xchg + ((size_t)(fpt*2 + cur))*512 + tid*2;
      u64x2 v;
      v[0] = __hip_atomic_load(dp+0, __ATOMIC_RELAXED, __HIP_MEMORY_SCOPE_AGENT);
      v[1] = __hip_atomic_load(dp+1, __ATOMIC_RELAXED, __HIP_MEMORY_SCOPE_AGENT);
      const int glp = tgl + (1-role)*16;
      f16* dq = hn + trow*256 + ((glp ^ (trow&7))<<3);
      *(u64x2*)dq = v;
    }
    __syncthreads();                                        // D: hn full
  }

  const f16* hf = hbuf + (SL&1)*4096;
  // final mask row (mdec role0)
  if (MODE==1 && role==0){
    const int mb = tid>>4, jj = tid&15;
    float s = 0.f;
    #pragma unroll
    for (int k=0;k<16;++k){ const int j = jj + k*16; s += (float)hf[hswz(mb, j)]*mlwf[j]; }
    s += __shfl_xor(s,1,64); s += __shfl_xor(s,2,64);
    s += __shfl_xor(s,4,64); s += __shfl_xor(s,8,64);
    if (jj==0) out_mask[(size_t)(slice*SL + SL-1)*BB + b0 + mb] = s + mlb;
  }
  // h_state writeback (own half)
  #pragma unroll
  for (int q=0;q<2;++q){
    const int j = (role*8 + wid*2 + q)*16 + l15;
    #pragma unroll
    for (int r=0;r<4;++r)
      h_state[(size_t)(b0+bi0+r)*256 + j] = hf[hswz(bi0+r, j)];
  }
  if (MODE==2){
    #pragma unroll
    for (int q=0;q<2;++q){
      const int j = (role*8 + wid*2 + q)*16 + l15;
      #pragma unroll
      for (int r=0;r<4;++r){
        const size_t idx = (size_t)(b0+bi0+r)*256 + j;
        hpsum[idx] = hpsum[idx] + psum[q][r];
      }
    }
  }
}

// 96 blocks: pp = bid%48 (0..15 mdec bt, 16..31 pdec bt, 32..47 enc bt),
// role = bid/48 -> pair (bid, bid+48) lands on the same XCD (48 % 8 == 0).
__global__ __launch_bounds__(256,1) void rec_kernel(
  const float* __restrict__ seq, const float* __restrict__ dpad,
  const float* __restrict__ enc_wih, const float* __restrict__ enc_bih, const float* __restrict__ enc_bhh,
  const float* __restrict__ mdec_bhh, const float* __restrict__ pdec_bhh,
  const float* __restrict__ mlin_w, const float* __restrict__ mlin_b,
  const f16* __restrict__ wfrag_enc, const f16* __restrict__ wfrag_m, const f16* __restrict__ wfrag_p,
  f16* __restrict__ he_st, f16* __restrict__ hm_st, f16* __restrict__ hp_st,
  f16* __restrict__ he_buf, const f16* __restrict__ gi_buf,
  float* __restrict__ hpsum, float* __restrict__ out_mask,
  u64* __restrict__ xchg, int* __restrict__ flags,
  int dec_slice, int enc_slice, int SL)
{
  __shared__ __align__(16) unsigned char smem[16384 + 128 + 1024 + 512];
  const int bid = blockIdx.x;
  const int pp = bid % 48, role = bid / 48;
  if (pp < 16){
    if (dec_slice < 0) return;
    const int bt = pp;
    gru_run<1>(role, bt, dec_slice, SL, wfrag_m, nullptr, mdec_bhh, nullptr, nullptr, nullptr,
               gi_buf + (size_t)bt*1536*16, hm_st, nullptr, mlin_w, mlin_b, out_mask, nullptr,
               xchg, flags, smem);
  } else if (pp < 32){
    if (dec_slice < 0) return;
    const int bt = pp - 16;
    gru_run<2>(role, bt, dec_slice, SL, wfrag_p, nullptr, pdec_bhh, nullptr, nullptr, nullptr,
               gi_buf + ((size_t)bt*1536 + 768)*16, hp_st, nullptr, nullptr, nullptr, nullptr, hpsum,
               xchg, flags, smem);
  } else {
    if (enc_slice < 0) return;
    const int bt = pp - 32;
    gru_run<0>(role, bt, enc_slice, SL, wfrag_enc, enc_bih, enc_bhh, enc_wih, seq, dpad,
               nullptr, he_st, he_buf, nullptr, nullptr, nullptr, nullptr,
               xchg, flags, smem);
  }
}

// =====================================================================
// GI: gi[t][b][n] = he[t][b][:] . w_ih_cat[n][:] + bih_cat[n]
// =====================================================================
__global__ __launch_bounds__(256,4) void gi_kernel(
  const f16* __restrict__ he_buf, const f16* __restrict__ wfrag_gi,
  const float* __restrict__ mdec_bih, const float* __restrict__ pdec_bih,
  f16* __restrict__ gi_buf)
{
  const int ts = blockIdx.x >> 2;
  const int bq = blockIdx.x & 3;
  const int tid = threadIdx.x, lane = tid&63, wid = tid>>6;
  const int l15 = lane&15, lhi = lane>>4;
  __shared__ f16 het[64*264];
  {
    const uint4* src = (const uint4*)(he_buf + ((size_t)ts*BB + bq*64)*HH);
    uint4* dst = (uint4*)het;
    #pragma unroll
    for (int k=0;k<8;++k){
      const int i = tid + k*256;
      dst[(i>>5)*33 + (i&31)] = src[i];
    }
  }
  __syncthreads();
  for (int mi=0; mi<24; ++mi){
    const int mt = wid*24 + mi;
    const int row0 = mt*16 + lhi*4;
    float bb[4];
    #pragma unroll
    for (int r=0;r<4;++r){
      const int rw = row0 + r;
      bb[r] = (rw < 768) ? mdec_bih[rw] : pdec_bih[rw-768];
    }
    f32x4 acc[4] = {{0,0,0,0},{0,0,0,0},{0,0,0,0},{0,0,0,0}};
    #pragma unroll
    for (int ks=0;ks<8;++ks){
      const f16x8 a = *(const f16x8*)(wfrag_gi + ((size_t)(mt*8+ks)*64 + lane)*8);
      #pragma unroll
      for (int bt=0;bt<4;++bt){
        const f16x8 b = *(const f16x8*)(het + (bt*16+l15)*264 + ks*32 + lhi*8);
        acc[bt] = __builtin_amdgcn_mfma_f32_16x16x32_f16(a, b, acc[bt], 0,0,0);
      }
    }
    #pragma unroll
    for (int bt=0;bt<4;++bt){
      const int btg = bq*4 + bt;
      const size_t base = (((size_t)ts*16 + btg)*1536 + (size_t)mt*16 + lhi*4)*16 + l15;
      #pragma unroll
      for (int r=0;r<4;++r) gi_buf[base + (size_t)r*16] = (f16)(acc[bt][r] + bb[r]);
    }
  }
}

// =====================================================================
// PRED: pred[b][p] = (hpsum[b]/512) . plin_w[p] + plin_b[p]
// =====================================================================
__global__ __launch_bounds__(256,1) void pred_kernel(
  const float* __restrict__ hpsum, const float* __restrict__ plin_w,
  const float* __restrict__ plin_b, float* __restrict__ out)
{
  __shared__ float hs[256];
  const int p = threadIdx.x;
  const float bias = plin_b[p];
  for (int bb=0; bb<4; ++bb){
    const int b = blockIdx.x*4 + bb;
    __syncthreads();
    hs[p] = hpsum[(size_t)b*256 + p];
    __syncthreads();
    float acc = 0.f;
    const float4* wrow = (const float4*)(plin_w + (size_t)p*256);
    #pragma unroll 4
    for (int k4=0;k4<64;++k4){
      const float4 w = wrow[k4];
      acc += hs[k4*4+0]*w.x + hs[k4*4+1]*w.y + hs[k4*4+2]*w.z + hs[k4*4+3]*w.w;
    }
    out[131072 + (size_t)b*256 + p] = acc*(1.f/512.f) + bias;
  }
}

// =====================================================================
extern "C" void kernel_launch(void* const* d_in, const int* in_sizes, int n_in,
                              void* d_out, int out_size, void* d_ws, size_t ws_size,
                              hipStream_t stream)
{
  const float* seq      = (const float*)d_in[0];
  const float* dpad     = (const float*)d_in[1];
  const float* h0e      = (const float*)d_in[2];
  const float* h0m      = (const float*)d_in[3];
  const float* h0p      = (const float*)d_in[4];
  const float* enc_wih  = (const float*)d_in[5];
  const float* enc_whh  = (const float*)d_in[6];
  const float* enc_bih  = (const float*)d_in[7];
  const float* enc_bhh  = (const float*)d_in[8];
  const float* mdec_wih = (const float*)d_in[9];
  const float* mdec_whh = (const float*)d_in[10];
  const float* mdec_bih = (const float*)d_in[11];
  const float* mdec_bhh = (const float*)d_in[12];
  const float* mlin_w   = (const float*)d_in[13];
  const float* mlin_b   = (const float*)d_in[14];
  const float* pdec_wih = (const float*)d_in[15];
  const float* pdec_whh = (const float*)d_in[16];
  const float* pdec_bih = (const float*)d_in[17];
  const float* pdec_bhh = (const float*)d_in[18];
  const float* plin_w   = (const float*)d_in[19];
  const float* plin_b   = (const float*)d_in[20];
  float* out = (float*)d_out;

  char* ws = (char*)d_ws;
  f16* wfrag_enc = (f16*)(ws + O_WFRAG_ENC);
  f16* wfrag_m   = (f16*)(ws + O_WFRAG_M);
  f16* wfrag_p   = (f16*)(ws + O_WFRAG_P);
  f16* wfrag_gi  = (f16*)(ws + O_WFRAG_GI);
  f16* he_st     = (f16*)(ws + O_HE_ST);
  f16* hm_st     = (f16*)(ws + O_HM_ST);
  f16* hp_st     = (f16*)(ws + O_HP_ST);
  float* hpsum   = (float*)(ws + O_HPSUM);
  u64* xchg      = (u64*)(ws + O_XCHG);
  int* flags     = (int*)(ws + O_FLAGS);

  int SL = 64;
  while (SL > 1 && (size_t)O_DYN + (size_t)SL*DYN_PER_STEP > ws_size) SL >>= 1;
  const int S = TT / SL;
  f16* he_buf = (f16*)(ws + O_DYN);
  f16* gi_buf = (f16*)(ws + O_DYN + (size_t)SL*131072u);

  prep_kernel<<<dim3(4096), dim3(256), 0, stream>>>(
      enc_whh, mdec_whh, pdec_whh, mdec_wih, pdec_wih, h0e, h0m, h0p,
      wfrag_enc, wfrag_m, wfrag_p, wfrag_gi, he_st, hm_st, hp_st, hpsum, flags);

  // encoder slice 0 only
  rec_kernel<<<dim3(96), dim3(256), 0, stream>>>(
      seq, dpad, enc_wih, enc_bih, enc_bhh, mdec_bhh, pdec_bhh,
      mlin_w, mlin_b, wfrag_enc, wfrag_m, wfrag_p, he_st, hm_st, hp_st,
      he_buf, gi_buf, hpsum, out, xchg, flags, -1, 0, SL);
  gi_kernel<<<dim3(SL*4), dim3(256), 0, stream>>>(he_buf, wfrag_gi, mdec_bih, pdec_bih, gi_buf);

  for (int s=0; s<S; ++s){
    const int enc_s = (s+1 < S) ? (s+1) : -1;
    rec_kernel<<<dim3(96), dim3(256), 0, stream>>>(
        seq, dpad, enc_wih, enc_bih, enc_bhh, mdec_bhh, pdec_bhh,
        mlin_w, mlin_b, wfrag_enc, wfrag_m, wfrag_p, he_st, hm_st, hp_st,
        he_buf, gi_buf, hpsum, out, xchg, flags, s, enc_s, SL);
    if (enc_s >= 0)
      gi_kernel<<<dim3(SL*4), dim3(256), 0, stream>>>(he_buf, wfrag_gi, mdec_bih, pdec_bih, gi_buf);
  }

  pred_kernel<<<dim3(64), dim3(256), 0, stream>>>(hpsum, plin_w, plin_b, out);
}